// Round 1
// baseline (445.544 us; speedup 1.0000x reference)
//
#include <hip/hip_runtime.h>
#include <cstdint>
#include <cstddef>

#define NTOK 4096      // H*W
#define HD 64          // head dim
#define CDIM 512       // channels
#define NPAIRS 64      // B * num_heads
#define K1_SPLIT 16
#define K1_TOK (NTOK / K1_SPLIT)   // 256 tokens per K1 block
#define EPS_F 1e-6f
#define EPS_LN 1e-5f
#define ATT_SCALE 0.125f           // hd^-0.5

// ---------------------------------------------------------------------------
// Kernel 1: kv[pair][d][e] = scale * sum_n kf[n][d]*v[n][e];  ksum[pair][d]
// ---------------------------------------------------------------------------
__global__ __launch_bounds__(256) void k_kvsum(const float* __restrict__ kin,
                                               const float* __restrict__ vin,
                                               const float* __restrict__ fm_w,
                                               const float* __restrict__ fm_b,
                                               float* __restrict__ kv_g,
                                               float* __restrict__ ksum_g)
{
    __shared__ float ktT[64][65];   // [n][d], pad 65 -> conflict-free col writes
    __shared__ float vtT[64][65];   // [n][e]
    __shared__ float kf[64][65];    // [n][e]
    __shared__ float b_lds[64];

    const int tid = threadIdx.x;
    const int pair = blockIdx.x >> 4;          // / K1_SPLIT
    const int split = blockIdx.x & (K1_SPLIT - 1);
    const int bb = pair >> 3, hh = pair & 7;
    const float* kb = kin + (size_t)(bb * CDIM + hh * HD) * NTOK;
    const float* vb = vin + (size_t)(bb * CDIM + hh * HD) * NTOK;

    if (tid < 64) b_lds[tid] = fm_b[tid];

    // kv-phase mapping: thread owns 4x4 tile (d0..d0+3, e0..e0+3)
    const int d0 = (tid >> 4) * 4;
    const int e0 = (tid & 15) * 4;
    float kvacc[4][4] = {{0.f, 0.f, 0.f, 0.f}, {0.f, 0.f, 0.f, 0.f},
                         {0.f, 0.f, 0.f, 0.f}, {0.f, 0.f, 0.f, 0.f}};
    float ksacc = 0.f;

    // feature-phase mapping: thread computes kf[fn][e0f..e0f+15]
    const int fn = tid & 63;
    const int e0f = (tid >> 6) * 16;
    const float4* wg4 = (const float4*)fm_w;   // [e][d/4], wave-uniform reads

    for (int chunk = 0; chunk < K1_TOK / 64; ++chunk) {
        const int n0 = split * K1_TOK + chunk * 64;
        __syncthreads();   // previous chunk's LDS reads done before overwrite
        // ---- stage: load 64d x 64n of K and V, transposed into LDS ----
        #pragma unroll
        for (int r = 0; r < 4; ++r) {
            const int idx = tid + r * 256;       // 1024 float4s
            const int d = idx >> 4;
            const int nn = (idx & 15) * 4;
            const float4 kx = *(const float4*)(kb + (size_t)d * NTOK + n0 + nn);
            ktT[nn + 0][d] = kx.x; ktT[nn + 1][d] = kx.y;
            ktT[nn + 2][d] = kx.z; ktT[nn + 3][d] = kx.w;
            const float4 vx = *(const float4*)(vb + (size_t)d * NTOK + n0 + nn);
            vtT[nn + 0][d] = vx.x; vtT[nn + 1][d] = vx.y;
            vtT[nn + 2][d] = vx.z; vtT[nn + 3][d] = vx.w;
        }
        __syncthreads();

        // ---- feature map: kf[fn][e] = elu(sum_d ktT[fn][d]*W[e][d]+b)+eps ----
        float acc[16];
        #pragma unroll
        for (int j = 0; j < 16; ++j) acc[j] = b_lds[e0f + j];
        #pragma unroll 4
        for (int d4 = 0; d4 < 16; ++d4) {
            const float k0 = ktT[fn][d4 * 4 + 0];
            const float k1 = ktT[fn][d4 * 4 + 1];
            const float k2 = ktT[fn][d4 * 4 + 2];
            const float k3 = ktT[fn][d4 * 4 + 3];
            #pragma unroll
            for (int j = 0; j < 16; ++j) {
                const float4 w4 = wg4[(e0f + j) * 16 + d4];
                acc[j] = fmaf(k0, w4.x, fmaf(k1, w4.y, fmaf(k2, w4.z, fmaf(k3, w4.w, acc[j]))));
            }
        }
        #pragma unroll
        for (int j = 0; j < 16; ++j) {
            float y = acc[j];
            y = (y > 0.f) ? y : expm1f(y);
            kf[fn][e0f + j] = y + EPS_F;
        }
        __syncthreads();

        // ---- kv accumulate over this chunk's 64 tokens ----
        #pragma unroll 8
        for (int n = 0; n < 64; ++n) {
            float av[4], bv[4];
            #pragma unroll
            for (int i = 0; i < 4; ++i) av[i] = kf[n][d0 + i];
            #pragma unroll
            for (int j = 0; j < 4; ++j) bv[j] = vtT[n][e0 + j];
            #pragma unroll
            for (int i = 0; i < 4; ++i)
                #pragma unroll
                for (int j = 0; j < 4; ++j)
                    kvacc[i][j] = fmaf(av[i], bv[j], kvacc[i][j]);
        }
        // ---- ksum (wave 0 only; wave-uniform branch) ----
        if (tid < 64) {
            #pragma unroll 8
            for (int n = 0; n < 64; ++n) ksacc += kf[n][tid];
        }
    }

    float* kvp = kv_g + (size_t)pair * (HD * HD);
    #pragma unroll
    for (int i = 0; i < 4; ++i)
        #pragma unroll
        for (int j = 0; j < 4; ++j)
            atomicAdd(&kvp[(d0 + i) * HD + (e0 + j)], kvacc[i][j] * ATT_SCALE);
    if (tid < 64) atomicAdd(&ksum_g[(size_t)pair * HD + tid], ksacc);
}

// ---------------------------------------------------------------------------
// Kernel 2: out[n][e] = (qf[n]·kv[:,e]) / (qf[n]·ksum + eps), pre-LN layout
// ---------------------------------------------------------------------------
__global__ __launch_bounds__(256) void k_qout(const float* __restrict__ qin,
                                              const float* __restrict__ fm_w,
                                              const float* __restrict__ fm_b,
                                              const float* __restrict__ kv_g,
                                              const float* __restrict__ ksum_g,
                                              float* __restrict__ outp)
{
    __shared__ float qtT[64][65];                        // [n][d]
    __shared__ float qf[64][65];                         // [n][e]
    __shared__ __align__(16) float kvs[64][64];          // [d][e]
    __shared__ float b_lds[64];
    __shared__ float ks_lds[64];
    __shared__ float norm_lds[64];

    const int tid = threadIdx.x;
    const int pair = blockIdx.x >> 6;       // 64 chunks per pair
    const int chunk = blockIdx.x & 63;
    const int n0 = chunk * 64;
    const int bb = pair >> 3, hh = pair & 7;
    const float* qb = qin + (size_t)(bb * CDIM + hh * HD) * NTOK;

    // load kv tile + ksum + bias
    const float4* kv4 = (const float4*)(kv_g + (size_t)pair * (HD * HD));
    float4* kvs4 = (float4*)&kvs[0][0];
    #pragma unroll
    for (int i = 0; i < 4; ++i) kvs4[tid + i * 256] = kv4[tid + i * 256];
    if (tid < 64) {
        b_lds[tid] = fm_b[tid];
        ks_lds[tid] = ksum_g[(size_t)pair * HD + tid];
    }
    // stage q chunk transposed
    #pragma unroll
    for (int r = 0; r < 4; ++r) {
        const int idx = tid + r * 256;
        const int d = idx >> 4;
        const int nn = (idx & 15) * 4;
        const float4 qx = *(const float4*)(qb + (size_t)d * NTOK + n0 + nn);
        qtT[nn + 0][d] = qx.x; qtT[nn + 1][d] = qx.y;
        qtT[nn + 2][d] = qx.z; qtT[nn + 3][d] = qx.w;
    }
    __syncthreads();

    // feature map -> qf
    const int fn = tid & 63;
    const int e0f = (tid >> 6) * 16;
    const float4* wg4 = (const float4*)fm_w;
    {
        float acc[16];
        #pragma unroll
        for (int j = 0; j < 16; ++j) acc[j] = b_lds[e0f + j];
        #pragma unroll 4
        for (int d4 = 0; d4 < 16; ++d4) {
            const float q0 = qtT[fn][d4 * 4 + 0];
            const float q1 = qtT[fn][d4 * 4 + 1];
            const float q2 = qtT[fn][d4 * 4 + 2];
            const float q3 = qtT[fn][d4 * 4 + 3];
            #pragma unroll
            for (int j = 0; j < 16; ++j) {
                const float4 w4 = wg4[(e0f + j) * 16 + d4];
                acc[j] = fmaf(q0, w4.x, fmaf(q1, w4.y, fmaf(q2, w4.z, fmaf(q3, w4.w, acc[j]))));
            }
        }
        #pragma unroll
        for (int j = 0; j < 16; ++j) {
            float y = acc[j];
            y = (y > 0.f) ? y : expm1f(y);
            qf[fn][e0f + j] = y + EPS_F;
        }
    }
    __syncthreads();

    if (tid < 64) {
        float s = 0.f;
        #pragma unroll 8
        for (int d = 0; d < 64; ++d) s = fmaf(qf[tid][d], ks_lds[d], s);
        norm_lds[tid] = s + EPS_F;
    }
    __syncthreads();

    // out GEMM: thread owns 4n x 4e tile; n-major mapping for coalesced stores
    const int nn0 = (tid & 15) * 4;
    const int ee0 = (tid >> 4) * 4;
    float o[4][4] = {{0.f, 0.f, 0.f, 0.f}, {0.f, 0.f, 0.f, 0.f},
                     {0.f, 0.f, 0.f, 0.f}, {0.f, 0.f, 0.f, 0.f}};
    #pragma unroll 8
    for (int d = 0; d < 64; ++d) {
        float av[4];
        #pragma unroll
        for (int i = 0; i < 4; ++i) av[i] = qf[nn0 + i][d];
        const float4 kb4 = *(const float4*)&kvs[d][ee0];
        #pragma unroll
        for (int i = 0; i < 4; ++i) {
            o[i][0] = fmaf(av[i], kb4.x, o[i][0]);
            o[i][1] = fmaf(av[i], kb4.y, o[i][1]);
            o[i][2] = fmaf(av[i], kb4.z, o[i][2]);
            o[i][3] = fmaf(av[i], kb4.w, o[i][3]);
        }
    }
    float rn[4];
    #pragma unroll
    for (int i = 0; i < 4; ++i) rn[i] = 1.f / norm_lds[nn0 + i];

    float* ob = outp + (size_t)(bb * CDIM + hh * HD) * NTOK + n0;
    #pragma unroll
    for (int j = 0; j < 4; ++j) {
        float4 w;
        w.x = o[0][j] * rn[0];
        w.y = o[1][j] * rn[1];
        w.z = o[2][j] * rn[2];
        w.w = o[3][j] * rn[3];
        *(float4*)(ob + (size_t)(ee0 + j) * NTOK + nn0) = w;
    }
}

// ---------------------------------------------------------------------------
// Kernel 3: in-place LayerNorm over C per spatial position
// ---------------------------------------------------------------------------
__global__ __launch_bounds__(256) void k_layernorm(float* __restrict__ io,
                                                   const float* __restrict__ ln_w,
                                                   const float* __restrict__ ln_b)
{
    __shared__ float xs[512][33];   // [c][n_local], pad 33
    __shared__ float mu_s[32];
    __shared__ float rs_s[32];

    const int tid = threadIdx.x;
    const int bb = blockIdx.x >> 7;        // 128 chunks of 32 positions per b
    const int chunk = blockIdx.x & 127;
    const int n0 = chunk * 32;
    float* base = io + (size_t)bb * CDIM * NTOK + n0;

    #pragma unroll
    for (int i = 0; i < 16; ++i) {
        const int idx = tid + i * 256;           // 4096 float4s
        const int c = idx >> 3;
        const int f4 = (idx & 7) * 4;
        const float4 vx = *(const float4*)(base + (size_t)c * NTOK + f4);
        xs[c][f4 + 0] = vx.x; xs[c][f4 + 1] = vx.y;
        xs[c][f4 + 2] = vx.z; xs[c][f4 + 3] = vx.w;
    }
    __syncthreads();

    const int n = tid >> 3;     // 0..31
    const int p = tid & 7;      // 8 partial-sum lanes per position
    float s = 0.f, s2 = 0.f;
    #pragma unroll 8
    for (int ci = 0; ci < 64; ++ci) {
        const int c = p * 64 + ((ci + p * 8) & 63);   // phase shift: no bank clash
        const float x = xs[c][n];
        s += x;
        s2 = fmaf(x, x, s2);
    }
    s += __shfl_xor(s, 1, 64);  s2 += __shfl_xor(s2, 1, 64);
    s += __shfl_xor(s, 2, 64);  s2 += __shfl_xor(s2, 2, 64);
    s += __shfl_xor(s, 4, 64);  s2 += __shfl_xor(s2, 4, 64);
    if (p == 0) {
        const float mu = s * (1.f / 512.f);
        const float var = s2 * (1.f / 512.f) - mu * mu;
        mu_s[n] = mu;
        rs_s[n] = rsqrtf(var + EPS_LN);
    }
    __syncthreads();

    #pragma unroll
    for (int i = 0; i < 16; ++i) {
        const int idx = tid + i * 256;
        const int c = idx >> 3;
        const int f4 = (idx & 7) * 4;
        const float w = ln_w[c];
        const float b2 = ln_b[c];
        float4 ov;
        ov.x = (xs[c][f4 + 0] - mu_s[f4 + 0]) * rs_s[f4 + 0] * w + b2;
        ov.y = (xs[c][f4 + 1] - mu_s[f4 + 1]) * rs_s[f4 + 1] * w + b2;
        ov.z = (xs[c][f4 + 2] - mu_s[f4 + 2]) * rs_s[f4 + 2] * w + b2;
        ov.w = (xs[c][f4 + 3] - mu_s[f4 + 3]) * rs_s[f4 + 3] * w + b2;
        *(float4*)(base + (size_t)c * NTOK + f4) = ov;
    }
}

// ---------------------------------------------------------------------------
extern "C" void kernel_launch(void* const* d_in, const int* in_sizes, int n_in,
                              void* d_out, int out_size, void* d_ws, size_t ws_size,
                              hipStream_t stream) {
    (void)in_sizes; (void)n_in; (void)out_size; (void)ws_size;
    const float* q    = (const float*)d_in[0];
    const float* k    = (const float*)d_in[1];
    const float* v    = (const float*)d_in[2];
    const float* fm_w = (const float*)d_in[3];
    const float* fm_b = (const float*)d_in[4];
    const float* ln_w = (const float*)d_in[5];
    const float* ln_b = (const float*)d_in[6];
    float* out = (float*)d_out;

    float* kv_ws   = (float*)d_ws;                       // 64 * 64 * 64 floats
    float* ksum_ws = kv_ws + (size_t)NPAIRS * HD * HD;   // 64 * 64 floats

    hipMemsetAsync(d_ws, 0, (size_t)(NPAIRS * HD * HD + NPAIRS * HD) * sizeof(float), stream);

    k_kvsum<<<NPAIRS * K1_SPLIT, 256, 0, stream>>>(k, v, fm_w, fm_b, kv_ws, ksum_ws);
    k_qout<<<NPAIRS * (NTOK / 64), 256, 0, stream>>>(q, fm_w, fm_b, kv_ws, ksum_ws, out);
    k_layernorm<<<8 * (NTOK / 32), 256, 0, stream>>>(out, ln_w, ln_b);
}

// Round 4
// 315.787 us; speedup vs baseline: 1.4109x; 1.4109x over previous
//
#include <hip/hip_runtime.h>
#include <cstdint>
#include <cstddef>

#define NTOK 4096      // H*W
#define HD 64          // head dim
#define CDIM 512       // channels
#define NPAIRS 64      // B * num_heads
#define K1_SPLIT 32    // blocks per pair in K1 (128 tokens each)
#define EPS_F 1e-6f
#define EPS_LN 1e-5f
#define ATT_SCALE 0.125f

__device__ __forceinline__ float elu_eps(float y) {
    return (y > 0.f ? y : (__expf(y) - 1.f)) + EPS_F;
}

// ---------------------------------------------------------------------------
// K1: kv[pair][d][e] += scale * sum_n kf[n][d] * v[n][e];  ksum[pair][d]
// kf = elu(K_tok W^T + b) + eps.  All fp32 (precision-critical, see r2/r3 PM).
// ---------------------------------------------------------------------------
__global__ __launch_bounds__(256) void k_kvsum(const float* __restrict__ kin,
                                               const float* __restrict__ vin,
                                               const float* __restrict__ fm_w,
                                               const float* __restrict__ fm_b,
                                               float* __restrict__ kv_g,
                                               float* __restrict__ ksum_g)
{
    __shared__ float ktT[64][65];                 // [n][d] transposed K chunk
    __shared__ float vtT[64][65];                 // [n][e] transposed V chunk
    __shared__ float kf[64][65];                  // [n][e_f] feature output
    __shared__ __align__(16) float Wl[64][64];    // [e][d] weight, block-resident

    const int tid = threadIdx.x;
    const int pair  = blockIdx.x >> 5;
    const int split = blockIdx.x & (K1_SPLIT - 1);
    const int bb = pair >> 3, hh = pair & 7;
    const float* kb = kin + (size_t)(bb * CDIM + hh * HD) * NTOK;
    const float* vb = vin + (size_t)(bb * CDIM + hh * HD) * NTOK;

    // stage W into LDS once (reads in feature phase are wave-uniform -> broadcast)
    {
        const float4* wg4 = (const float4*)fm_w;
        float4* wl4 = (float4*)&Wl[0][0];
        #pragma unroll
        for (int i = 0; i < 4; ++i) wl4[tid + i * 256] = wg4[tid + i * 256];
    }

    // feature-phase mapping: thread = (token fn, e-block e0f of 16)
    const int fn  = tid & 63;
    const int e0f = (tid >> 6) * 16;
    float bias[16];
    #pragma unroll
    for (int j = 0; j < 16; ++j) bias[j] = fm_b[e0f + j];

    // kv-phase mapping: thread owns 4x4 (d0+i, e0+j); e0==60 group also does ksum
    const int d0 = (tid >> 4) * 4;
    const int e0 = (tid & 15) * 4;
    const bool kslane = ((tid & 15) == 15);
    float kvacc[4][4] = {{0.f,0.f,0.f,0.f},{0.f,0.f,0.f,0.f},
                         {0.f,0.f,0.f,0.f},{0.f,0.f,0.f,0.f}};
    float ksacc[4] = {0.f, 0.f, 0.f, 0.f};

    for (int chunk = 0; chunk < 2; ++chunk) {
        const int n0 = split * 128 + chunk * 64;
        __syncthreads();   // prev chunk's LDS reads done (also covers W staging)

        // ---- stage K,V 64d x 64n transposed into LDS ----
        #pragma unroll
        for (int r = 0; r < 4; ++r) {
            const int idx = tid + r * 256;       // 1024 float4s
            const int d = idx >> 4;
            const int nn = (idx & 15) * 4;
            const float4 kx = *(const float4*)(kb + (size_t)d * NTOK + n0 + nn);
            ktT[nn + 0][d] = kx.x; ktT[nn + 1][d] = kx.y;
            ktT[nn + 2][d] = kx.z; ktT[nn + 3][d] = kx.w;
            const float4 vx = *(const float4*)(vb + (size_t)d * NTOK + n0 + nn);
            vtT[nn + 0][d] = vx.x; vtT[nn + 1][d] = vx.y;
            vtT[nn + 2][d] = vx.z; vtT[nn + 3][d] = vx.w;
        }
        __syncthreads();

        // ---- feature map: kf[fn][e] = elu(sum_d ktT[fn][d]*W[e][d]+b)+eps ----
        {
            float acc[16];
            #pragma unroll
            for (int j = 0; j < 16; ++j) acc[j] = bias[j];
            #pragma unroll 4
            for (int d4 = 0; d4 < 16; ++d4) {
                const float k0 = ktT[fn][d4 * 4 + 0];
                const float k1 = ktT[fn][d4 * 4 + 1];
                const float k2 = ktT[fn][d4 * 4 + 2];
                const float k3 = ktT[fn][d4 * 4 + 3];
                #pragma unroll
                for (int j = 0; j < 16; ++j) {
                    const float4 w4 = *(const float4*)&Wl[e0f + j][4 * d4];
                    acc[j] = fmaf(k0, w4.x, fmaf(k1, w4.y, fmaf(k2, w4.z, fmaf(k3, w4.w, acc[j]))));
                }
            }
            #pragma unroll
            for (int j = 0; j < 16; ++j) kf[fn][e0f + j] = elu_eps(acc[j]);
        }
        __syncthreads();

        // ---- kv accumulate (ksum folded in on the e0==60 lane group) ----
        #pragma unroll 4
        for (int n = 0; n < 64; ++n) {
            float av[4], bv[4];
            #pragma unroll
            for (int i = 0; i < 4; ++i) av[i] = kf[n][d0 + i];
            #pragma unroll
            for (int j = 0; j < 4; ++j) bv[j] = vtT[n][e0 + j];
            #pragma unroll
            for (int i = 0; i < 4; ++i)
                #pragma unroll
                for (int j = 0; j < 4; ++j)
                    kvacc[i][j] = fmaf(av[i], bv[j], kvacc[i][j]);
            if (kslane) {
                #pragma unroll
                for (int i = 0; i < 4; ++i) ksacc[i] += av[i];
            }
        }
    }

    float* kvp = kv_g + (size_t)pair * (HD * HD);
    #pragma unroll
    for (int i = 0; i < 4; ++i)
        #pragma unroll
        for (int j = 0; j < 4; ++j)
            atomicAdd(&kvp[(d0 + i) * HD + (e0 + j)], kvacc[i][j] * ATT_SCALE);
    if (kslane) {
        #pragma unroll
        for (int i = 0; i < 4; ++i)
            atomicAdd(&ksum_g[(size_t)pair * HD + d0 + i], ksacc[i]);
    }
}

// ---------------------------------------------------------------------------
// K2: out[n][e] = (qf[n]·kv[:,e]) / (qf[n]·ksum + eps), fp32
// ---------------------------------------------------------------------------
__global__ __launch_bounds__(256) void k_qout(const float* __restrict__ qin,
                                              const float* __restrict__ fm_w,
                                              const float* __restrict__ fm_b,
                                              const float* __restrict__ kv_g,
                                              const float* __restrict__ ksum_g,
                                              float* __restrict__ outp)
{
    __shared__ float qtT[64][65];                 // [n][d]
    __shared__ float qf[64][65];                  // [n][e_f]
    __shared__ __align__(16) float Wl[64][64];    // [e][d]
    __shared__ __align__(16) float kvs[64][64];   // [d][e]
    __shared__ float nred[4][64];                 // [wave][token] norm partials
    __shared__ float norm_lds[64];

    const int tid = threadIdx.x;
    const int pair  = blockIdx.x >> 6;
    const int chunk = blockIdx.x & 63;
    const int n0 = chunk * 64;
    const int bb = pair >> 3, hh = pair & 7;
    const float* qb = qin + (size_t)(bb * CDIM + hh * HD) * NTOK;

    // stage W + kv + Q (single barrier covers all)
    {
        const float4* wg4 = (const float4*)fm_w;
        float4* wl4 = (float4*)&Wl[0][0];
        #pragma unroll
        for (int i = 0; i < 4; ++i) wl4[tid + i * 256] = wg4[tid + i * 256];
        const float4* kv4 = (const float4*)(kv_g + (size_t)pair * (HD * HD));
        float4* kvs4 = (float4*)&kvs[0][0];
        #pragma unroll
        for (int i = 0; i < 4; ++i) kvs4[tid + i * 256] = kv4[tid + i * 256];
        #pragma unroll
        for (int r = 0; r < 4; ++r) {
            const int idx = tid + r * 256;
            const int d = idx >> 4;
            const int nn = (idx & 15) * 4;
            const float4 qx = *(const float4*)(qb + (size_t)d * NTOK + n0 + nn);
            qtT[nn + 0][d] = qx.x; qtT[nn + 1][d] = qx.y;
            qtT[nn + 2][d] = qx.z; qtT[nn + 3][d] = qx.w;
        }
    }

    const int fn  = tid & 63;
    const int wv  = tid >> 6;
    const int e0f = wv * 16;
    float bias[16], ksr[16];
    #pragma unroll
    for (int j = 0; j < 16; ++j) {
        bias[j] = fm_b[e0f + j];
        ksr[j]  = ksum_g[(size_t)pair * HD + e0f + j];
    }
    __syncthreads();

    // ---- feature map -> qf, with normalizer partial folded in ----
    {
        float acc[16];
        #pragma unroll
        for (int j = 0; j < 16; ++j) acc[j] = bias[j];
        #pragma unroll 4
        for (int d4 = 0; d4 < 16; ++d4) {
            const float q0 = qtT[fn][d4 * 4 + 0];
            const float q1 = qtT[fn][d4 * 4 + 1];
            const float q2 = qtT[fn][d4 * 4 + 2];
            const float q3 = qtT[fn][d4 * 4 + 3];
            #pragma unroll
            for (int j = 0; j < 16; ++j) {
                const float4 w4 = *(const float4*)&Wl[e0f + j][4 * d4];
                acc[j] = fmaf(q0, w4.x, fmaf(q1, w4.y, fmaf(q2, w4.z, fmaf(q3, w4.w, acc[j]))));
            }
        }
        float np = 0.f;
        #pragma unroll
        for (int j = 0; j < 16; ++j) {
            const float v = elu_eps(acc[j]);
            qf[fn][e0f + j] = v;
            np = fmaf(v, ksr[j], np);
        }
        nred[wv][fn] = np;
    }
    __syncthreads();
    if (tid < 64)
        norm_lds[tid] = nred[0][tid] + nred[1][tid] + nred[2][tid] + nred[3][tid] + EPS_F;
    __syncthreads();

    // ---- out GEMM: thread owns 4n x 4e; n-major for coalesced stores ----
    const int nn0 = (tid & 15) * 4;
    const int ee0 = (tid >> 4) * 4;
    float o[4][4] = {{0.f,0.f,0.f,0.f},{0.f,0.f,0.f,0.f},
                     {0.f,0.f,0.f,0.f},{0.f,0.f,0.f,0.f}};
    #pragma unroll 8
    for (int d = 0; d < 64; ++d) {
        float av[4];
        #pragma unroll
        for (int i = 0; i < 4; ++i) av[i] = qf[nn0 + i][d];
        const float4 kb4 = *(const float4*)&kvs[d][ee0];
        #pragma unroll
        for (int i = 0; i < 4; ++i) {
            o[i][0] = fmaf(av[i], kb4.x, o[i][0]);
            o[i][1] = fmaf(av[i], kb4.y, o[i][1]);
            o[i][2] = fmaf(av[i], kb4.z, o[i][2]);
            o[i][3] = fmaf(av[i], kb4.w, o[i][3]);
        }
    }
    float rn[4];
    #pragma unroll
    for (int i = 0; i < 4; ++i) rn[i] = 1.f / norm_lds[nn0 + i];

    float* ob = outp + (size_t)(bb * CDIM + hh * HD) * NTOK + n0;
    #pragma unroll
    for (int j = 0; j < 4; ++j) {
        float4 w;
        w.x = o[0][j] * rn[0];
        w.y = o[1][j] * rn[1];
        w.z = o[2][j] * rn[2];
        w.w = o[3][j] * rn[3];
        *(float4*)(ob + (size_t)(ee0 + j) * NTOK + nn0) = w;
    }
}

// ---------------------------------------------------------------------------
// K3: in-place LayerNorm over C, 16 tokens/block, TWO-PASS variance
// ---------------------------------------------------------------------------
__global__ __launch_bounds__(256) void k_layernorm(float* __restrict__ io,
                                                   const float* __restrict__ ln_w,
                                                   const float* __restrict__ ln_b)
{
    __shared__ float xs[512][17];
    __shared__ float mu_s[16];
    __shared__ float rs_s[16];

    const int tid = threadIdx.x;
    const int bb = blockIdx.x >> 8;        // 256 chunks of 16 positions per b
    const int chunk = blockIdx.x & 255;
    const int n0 = chunk * 16;
    float* base = io + (size_t)bb * CDIM * NTOK + n0;

    #pragma unroll
    for (int i = 0; i < 8; ++i) {
        const int idx = tid + i * 256;           // 2048 float4s
        const int c = idx >> 2;
        const int f4 = (idx & 3) * 4;
        const float4 vx = *(const float4*)(base + (size_t)c * NTOK + f4);
        xs[c][f4 + 0] = vx.x; xs[c][f4 + 1] = vx.y;
        xs[c][f4 + 2] = vx.z; xs[c][f4 + 3] = vx.w;
    }
    __syncthreads();

    const int n = tid >> 4;     // 0..15
    const int p = tid & 15;     // 16 partial lanes per token
    // pass 1: mean
    float s = 0.f;
    #pragma unroll 8
    for (int ci = 0; ci < 32; ++ci) {
        const int c = p * 32 + ((ci + 2 * p) & 31);
        s += xs[c][n];
    }
    s += __shfl_xor(s, 1, 64);
    s += __shfl_xor(s, 2, 64);
    s += __shfl_xor(s, 4, 64);
    s += __shfl_xor(s, 8, 64);
    if (p == 0) mu_s[n] = s * (1.f / 512.f);
    __syncthreads();
    // pass 2: variance about the mean (no cancellation)
    const float mu = mu_s[n];
    float s2 = 0.f;
    #pragma unroll 8
    for (int ci = 0; ci < 32; ++ci) {
        const int c = p * 32 + ((ci + 2 * p) & 31);
        const float x = xs[c][n] - mu;
        s2 = fmaf(x, x, s2);
    }
    s2 += __shfl_xor(s2, 1, 64);
    s2 += __shfl_xor(s2, 2, 64);
    s2 += __shfl_xor(s2, 4, 64);
    s2 += __shfl_xor(s2, 8, 64);
    if (p == 0) rs_s[n] = rsqrtf(s2 * (1.f / 512.f) + EPS_LN);
    __syncthreads();

    #pragma unroll
    for (int i = 0; i < 8; ++i) {
        const int idx = tid + i * 256;
        const int c = idx >> 2;
        const int f4 = (idx & 3) * 4;
        const float w = ln_w[c];
        const float b2 = ln_b[c];
        float4 ov;
        ov.x = (xs[c][f4 + 0] - mu_s[f4 + 0]) * rs_s[f4 + 0] * w + b2;
        ov.y = (xs[c][f4 + 1] - mu_s[f4 + 1]) * rs_s[f4 + 1] * w + b2;
        ov.z = (xs[c][f4 + 2] - mu_s[f4 + 2]) * rs_s[f4 + 2] * w + b2;
        ov.w = (xs[c][f4 + 3] - mu_s[f4 + 3]) * rs_s[f4 + 3] * w + b2;
        *(float4*)(base + (size_t)c * NTOK + f4) = ov;
    }
}

// ---------------------------------------------------------------------------
extern "C" void kernel_launch(void* const* d_in, const int* in_sizes, int n_in,
                              void* d_out, int out_size, void* d_ws, size_t ws_size,
                              hipStream_t stream) {
    (void)in_sizes; (void)n_in; (void)out_size; (void)ws_size;
    const float* q    = (const float*)d_in[0];
    const float* k    = (const float*)d_in[1];
    const float* v    = (const float*)d_in[2];
    const float* fm_w = (const float*)d_in[3];
    const float* fm_b = (const float*)d_in[4];
    const float* ln_w = (const float*)d_in[5];
    const float* ln_b = (const float*)d_in[6];
    float* out = (float*)d_out;

    float* kv_ws   = (float*)d_ws;                       // [64][64][64] (d, e)
    float* ksum_ws = kv_ws + (size_t)NPAIRS * HD * HD;   // [64][64]

    hipMemsetAsync(d_ws, 0, (size_t)(NPAIRS * HD * HD + NPAIRS * HD) * sizeof(float), stream);

    k_kvsum<<<NPAIRS * K1_SPLIT, 256, 0, stream>>>(k, v, fm_w, fm_b, kv_ws, ksum_ws);
    k_qout<<<NPAIRS * (NTOK / 64), 256, 0, stream>>>(q, fm_w, fm_b, kv_ws, ksum_ws, out);
    k_layernorm<<<8 * (NTOK / 16), 256, 0, stream>>>(out, ln_w, ln_b);
}